// Round 8
// baseline (415.693 us; speedup 1.0000x reference)
//
#include <hip/hip_runtime.h>
#include <math.h>

#define B 1024
#define N 2048
#define M 128
#define C 512
#define OD (M + 6)
#define EPSF 1e-8f
#define CHUNK 256
#define NCHUNK 8           // N / CHUNK
#define NGRP 32            // concurrent b-groups
#define ITERS 32           // B / NGRP
#define GRID_F 256         // NCHUNK * NGRP = 1 block/CU
#define AGENT __HIP_MEMORY_SCOPE_AGENT

__device__ __forceinline__ float softplusf(float x) {
    return fmaxf(x, 0.f) + log1pf(expf(-fabsf(x)));
}
__device__ __forceinline__ float sigmoidf_(float x) {
    return 1.f / (1.f + expf(-x));
}

// LDS-only barrier (no vmcnt drain: in-flight global loads unaffected)
__device__ __forceinline__ void bar_lds() {
    asm volatile("s_waitcnt lgkmcnt(0)" ::: "memory");
    __builtin_amdgcn_s_barrier();
}

// Kernel 1: o = x @ W.T + b; k (first M cols) + scalar head params.
__global__ __launch_bounds__(256) void k_head(
    const float* __restrict__ x, const float* __restrict__ W,
    const float* __restrict__ bias, float* __restrict__ kbuf,
    float* __restrict__ params)
{
    const int b = blockIdx.x;
    __shared__ float xs[C];
    __shared__ float os[OD];
    __shared__ float red[128];

    for (int i = threadIdx.x; i < C; i += 256) xs[i] = x[(size_t)b * C + i];
    __syncthreads();

    if (threadIdx.x < OD) {
        const int j = threadIdx.x;
        const float4* wr = (const float4*)(W + (size_t)j * C);
        float acc = 0.f;
#pragma unroll 8
        for (int c = 0; c < C / 4; ++c) {
            float4 wv = wr[c];
            acc = fmaf(wv.x, xs[4 * c + 0], acc);
            acc = fmaf(wv.y, xs[4 * c + 1], acc);
            acc = fmaf(wv.z, xs[4 * c + 2], acc);
            acc = fmaf(wv.w, xs[4 * c + 3], acc);
        }
        os[j] = acc + bias[j];
    }
    __syncthreads();

    if (threadIdx.x < M) {
        float v = os[threadIdx.x];
        kbuf[(size_t)b * M + threadIdx.x] = v;
        red[threadIdx.x] = v * v;
    }
    __syncthreads();
    for (int s = 64; s > 0; s >>= 1) {
        if (threadIdx.x < s) red[threadIdx.x] += red[threadIdx.x + s];
        __syncthreads();
    }
    if (threadIdx.x == 0) {
        float kn = sqrtf(red[0]);
        float beta = softplusf(os[M]);
        float g = sigmoidf_(os[M + 1]);
        float a0 = os[M + 2], a1 = os[M + 3], a2 = os[M + 4];
        float mx = fmaxf(a0, fmaxf(a1, a2));
        float e0 = expf(a0 - mx), e1 = expf(a1 - mx), e2 = expf(a2 - mx);
        float inv = 1.f / (e0 + e1 + e2);
        float gamma = 1.f + softplusf(os[M + 5]);
        float* p = params + (size_t)b * 8;
        p[0] = beta; p[1] = g; p[2] = e0 * inv; p[3] = e1 * inv;
        p[4] = e2 * inv; p[5] = gamma; p[6] = kn; p[7] = 0.f;
    }
}

// One pipelined step. FC/KC/P0C/P1C: current (already loaded / in flight);
// FN/KN_/P0N/P1N: next-iteration buffers this step fills.
// Waves 1-7 prefetch right after the arrival; wave 0 (the spinner) defers its
// share until after the spin, because its poll loops execute vmcnt(0).
#define STEP(IT, FC, KC, P0C, P1C, FN, KN_, P0N, P1N)                          \
{                                                                              \
    const int b  = bgrp * ITERS + (IT);                                        \
    const int bn = (b + 1 < B) ? (b + 1) : b;   /* clamp; last result unused */\
    float wp_t = 0.f, wpL = 0.f, wpR = 0.f;                                    \
    if (tid < CHUNK) wp_t = w_prev[(size_t)b * N + cid * CHUNK + tid];         \
    if (tid == 0) {                                                            \
        wpL = w_prev[(size_t)b * N + ((cid * CHUNK + N - 1) & (N - 1))];       \
        wpR = w_prev[(size_t)b * N + ((cid * CHUNK + CHUNK) & (N - 1))];       \
    }                                                                          \
    const float beta = P0C.x, kn = P1C.z;                                      \
    /* ---- phase A: e = exp(beta*cos_sim) for my 16 rows ---- */              \
    float myS = 0.f;                                                           \
    _Pragma("unroll")                                                          \
    for (int j = 0; j < 16; ++j) {                                             \
        float dot = FC[j].x * KC.x + FC[j].y * KC.y + FC[j].z * KC.z + FC[j].w * KC.w; \
        float sq  = FC[j].x * FC[j].x + FC[j].y * FC[j].y + FC[j].z * FC[j].z + FC[j].w * FC[j].w; \
        _Pragma("unroll")                                                      \
        for (int s = 16; s >= 1; s >>= 1) {                                    \
            dot += __shfl_xor(dot, s, 64);                                     \
            sq  += __shfl_xor(sq,  s, 64);                                     \
        }                                                                      \
        if (l32 == 0) {                                                        \
            const float z = beta * dot / (sqrtf(sq) * kn + EPSF);              \
            const float e = expf(z);                                           \
            eA[hw * 16 + j] = e;                                               \
            myS += e;                                                          \
        }                                                                      \
    }                                                                          \
    if (l32 == 0) partS[hw] = myS;                                             \
    bar_lds();   /* bar1: eA/partS visible */                                  \
    /* ---- publish + arrive (vmcnt(0) BEFORE any prefetch is issued) ---- */  \
    if (tid == 0) {                                                            \
        float S = 0.f;                                                         \
        _Pragma("unroll")                                                      \
        for (int h = 0; h < 16; ++h) S += partS[h];                            \
        __hip_atomic_store(&sPart[(size_t)b * NCHUNK + cid], S, __ATOMIC_RELAXED, AGENT); \
        __hip_atomic_store(&edgeE[((size_t)b * NCHUNK + cid) * 2 + 0], eA[0], __ATOMIC_RELAXED, AGENT); \
        __hip_atomic_store(&edgeE[((size_t)b * NCHUNK + cid) * 2 + 1], eA[CHUNK - 1], __ATOMIC_RELAXED, AGENT); \
        asm volatile("s_waitcnt vmcnt(0)" ::: "memory");                       \
        __hip_atomic_fetch_add(&cnt1[b], 1, __ATOMIC_RELAXED, AGENT);          \
    }                                                                          \
    /* ---- prefetch next chunk (waves 1-7): streams across spin+B+C+D ---- */ \
    const float* nb = mem + ((size_t)bn * N + cid * CHUNK) * M;                \
    if (wv != 0) {                                                             \
        _Pragma("unroll")                                                      \
        for (int j = 0; j < 16; ++j)                                           \
            FN[j] = ((const float4*)(nb + (size_t)(hw * 16 + j) * M))[l32];    \
        KN_ = ((const float4*)(kbuf + (size_t)bn * M))[l32];                   \
    }                                                                          \
    P0N = ((const float4*)(params + (size_t)bn * 8))[0];                       \
    P1N = ((const float4*)(params + (size_t)bn * 8))[1];                       \
    /* ---- spin (relaxed polls; wave 0 has no prefetch in flight) ---- */     \
    if (tid == 0) {                                                            \
        int tries = 0;                                                         \
        while (__hip_atomic_load(&cnt1[b], __ATOMIC_RELAXED, AGENT) < NCHUNK) {\
            __builtin_amdgcn_s_sleep(1);                                       \
            if (++tries > (1 << 22)) break;   /* failsafe: fail loud */        \
        }                                                                      \
        float St = 0.f;                                                        \
        _Pragma("unroll")                                                      \
        for (int c2 = 0; c2 < NCHUNK; ++c2)   /* fixed order: deterministic */ \
            St += __hip_atomic_load(&sPart[(size_t)b * NCHUNK + c2], __ATOMIC_RELAXED, AGENT); \
        bcast[0] = 1.f / St;                                                   \
        bcast[1] = __hip_atomic_load(&edgeE[((size_t)b * NCHUNK + ((cid + NCHUNK - 1) & (NCHUNK - 1))) * 2 + 1], __ATOMIC_RELAXED, AGENT); \
        bcast[2] = __hip_atomic_load(&edgeE[((size_t)b * NCHUNK + ((cid + 1) & (NCHUNK - 1))) * 2 + 0], __ATOMIC_RELAXED, AGENT); \
    }                                                                          \
    bar_lds();   /* bar2: bcast visible */                                     \
    /* ---- wave 0's deferred prefetch share ---- */                           \
    if (wv == 0) {                                                             \
        _Pragma("unroll")                                                      \
        for (int j = 0; j < 16; ++j)                                           \
            FN[j] = ((const float4*)(nb + (size_t)(hw * 16 + j) * M))[l32];    \
        KN_ = ((const float4*)(kbuf + (size_t)bn * M))[l32];                   \
    }                                                                          \
    /* ---- phase B: wg, conv3, pow, partial T ---- */                         \
    const float invS = bcast[0], eL = bcast[1], eR = bcast[2];                 \
    const float g = P0C.y, s0p = P0C.z, s1p = P0C.w, s2p = P1C.x, gamma = P1C.y; \
    if (tid < CHUNK)                                                           \
        wgA[tid + 1] = g * eA[tid] * invS + (1.f - g) * wp_t;                  \
    if (tid == 0) {                                                            \
        wgA[0]         = g * eL * invS + (1.f - g) * wpL;                      \
        wgA[CHUNK + 1] = g * eR * invS + (1.f - g) * wpR;                      \
    }                                                                          \
    bar_lds();   /* bar3: wgA visible */                                       \
    float myT = 0.f;                                                           \
    if (tid < CHUNK) {                                                         \
        const float wt = s0p * wgA[tid] + s1p * wgA[tid + 1] + s2p * wgA[tid + 2]; \
        const float pw = powf(wt, gamma);                                      \
        pwA[tid] = pw;                                                         \
        myT = pw;                                                              \
    }                                                                          \
    _Pragma("unroll")                                                          \
    for (int s = 32; s >= 1; s >>= 1) myT += __shfl_xor(myT, s, 64);           \
    if (lane == 0 && wv < 4) partT[wv] = myT;                                  \
    bar_lds();   /* bar4: pwA/partT visible */                                 \
    if (tid == 0) {                                                            \
        tPart[(size_t)b * NCHUNK + cid] = partT[0] + partT[1] + partT[2] + partT[3]; \
    }                                                                          \
    /* ---- phase C: unnormalized r partial from register-held chunk ---- */   \
    float4 acc = make_float4(0.f, 0.f, 0.f, 0.f);                              \
    _Pragma("unroll")                                                          \
    for (int j = 0; j < 16; ++j) {                                             \
        const float pw = pwA[hw * 16 + j];                                     \
        acc.x = fmaf(pw, FC[j].x, acc.x);                                      \
        acc.y = fmaf(pw, FC[j].y, acc.y);                                      \
        acc.z = fmaf(pw, FC[j].z, acc.z);                                      \
        acc.w = fmaf(pw, FC[j].w, acc.w);                                      \
    }                                                                          \
    acc.x += __shfl_xor(acc.x, 32, 64);                                        \
    acc.y += __shfl_xor(acc.y, 32, 64);                                        \
    acc.z += __shfl_xor(acc.z, 32, 64);                                        \
    acc.w += __shfl_xor(acc.w, 32, 64);                                        \
    if (half == 0) *(float4*)&redA[wv * 128 + l32 * 4] = acc;                  \
    bar_lds();   /* bar5: redA visible */                                      \
    if (tid < 128) {                                                           \
        float s = 0.f;                                                         \
        _Pragma("unroll")                                                      \
        for (int w2 = 0; w2 < 8; ++w2) s += redA[w2 * 128 + tid];              \
        rpart[((size_t)b * NCHUNK + cid) * 128 + tid] = s;                     \
    }                                                                          \
    /* ---- phase D: unnormalized w slice (k_norm scales) ---- */              \
    if (tid < CHUNK)                                                           \
        w_out[(size_t)b * N + cid * CHUNK + tid] = pwA[tid];                   \
    /* no trailing barrier: bar1..bar5 of next step order all LDS reuse */     \
}

// Single-mem-pass fused kernel v4: register double-buffered pipeline.
// 256 blocks (1/CU), 512 threads (8 waves). Block (cid=blockIdx>>5,
// bgrp=blockIdx&31): peers of a b share bgrp -> same blockIdx%8 -> same XCD.
// mem read exactly once; loads of iteration it+1 overlap sync+compute of it.
__global__ __launch_bounds__(512, 2) void k_fused(
    const float* __restrict__ mem, const float* __restrict__ kbuf,
    const float* __restrict__ params, const float* __restrict__ w_prev,
    float* __restrict__ w_out,
    float* __restrict__ sPart, float* __restrict__ tPart,
    int* __restrict__ cnt1, float* __restrict__ edgeE,
    float* __restrict__ rpart)
{
    __shared__ float eA[CHUNK];
    __shared__ float wgA[CHUNK + 2];
    __shared__ float pwA[CHUNK];
    __shared__ float redA[8 * 128];
    __shared__ float partS[16];
    __shared__ float partT[4];
    __shared__ float bcast[4];

    const int tid  = threadIdx.x;
    const int lane = tid & 63;
    const int wv   = tid >> 6;       // 0..7
    const int half = lane >> 5;
    const int l32  = lane & 31;
    const int hw   = wv * 2 + half;  // 0..15: half-wave id (16 rows each)

    const int cid  = blockIdx.x >> 5;   // 0..7
    const int bgrp = blockIdx.x & 31;   // peers share bgrp

    float4 fA[16], fB[16], kvA, kvB, p0A, p1A, p0B, p1B;

    // prologue: first chunk into the A buffers
    {
        const int b0 = bgrp * ITERS;
        const float* cb = mem + ((size_t)b0 * N + cid * CHUNK) * M;
#pragma unroll
        for (int j = 0; j < 16; ++j)
            fA[j] = ((const float4*)(cb + (size_t)(hw * 16 + j) * M))[l32];
        kvA = ((const float4*)(kbuf + (size_t)b0 * M))[l32];
        p0A = ((const float4*)(params + (size_t)b0 * 8))[0];
        p1A = ((const float4*)(params + (size_t)b0 * 8))[1];
    }

    for (int it = 0; it < ITERS; it += 2) {
        STEP(it,     fA, kvA, p0A, p1A, fB, kvB, p0B, p1B)
        STEP(it + 1, fB, kvB, p0B, p1B, fA, kvA, p0A, p1A)
    }
}

// Tiny epilogue: per b, T = sum of chunk partials; scale w in place; reduce r.
__global__ __launch_bounds__(256) void k_norm(
    const float* __restrict__ tPart, const float* __restrict__ rpart,
    float* __restrict__ w_out, float* __restrict__ r_out)
{
    const int b = blockIdx.x, tid = threadIdx.x;
    float T = 0.f;
#pragma unroll
    for (int c = 0; c < NCHUNK; ++c) T += tPart[(size_t)b * NCHUNK + c];
    const float invT = 1.f / (T + 1e-16f);

    float4* w4 = (float4*)(w_out + (size_t)b * N);
#pragma unroll
    for (int k = 0; k < 2; ++k) {
        float4 v = w4[tid + k * 256];
        v.x *= invT; v.y *= invT; v.z *= invT; v.w *= invT;
        w4[tid + k * 256] = v;
    }
    if (tid < 128) {
        float s = 0.f;
#pragma unroll
        for (int c = 0; c < NCHUNK; ++c)   // fixed order -> deterministic
            s += rpart[((size_t)b * NCHUNK + c) * 128 + tid];
        r_out[(size_t)b * M + tid] = s * invT;
    }
}

extern "C" void kernel_launch(void* const* d_in, const int* in_sizes, int n_in,
                              void* d_out, int out_size, void* d_ws, size_t ws_size,
                              hipStream_t stream) {
    const float* x      = (const float*)d_in[0];
    const float* w_prev = (const float*)d_in[1];
    const float* mem    = (const float*)d_in[2];
    const float* W      = (const float*)d_in[3];
    const float* bias   = (const float*)d_in[4];

    float* r_out = (float*)d_out;                 // B*M
    float* w_out = (float*)d_out + (size_t)B * M; // B*N

    float* ws     = (float*)d_ws;
    float* kbuf   = ws;                                    // B*M
    float* params = kbuf + (size_t)B * M;                  // B*8
    float* sPart  = params + (size_t)B * 8;                // B*NCHUNK
    float* tPart  = sPart + (size_t)B * NCHUNK;            // B*NCHUNK
    int*   cnt1   = (int*)(tPart + (size_t)B * NCHUNK);    // B ints
    float* edgeE  = (float*)(cnt1 + B);                    // B*NCHUNK*2
    float* rpart  = edgeE + (size_t)B * NCHUNK * 2;        // B*NCHUNK*128

    // arrival counters must be zero every call
    hipMemsetAsync(cnt1, 0, B * sizeof(int), stream);

    k_head<<<B, 256, 0, stream>>>(x, W, bias, kbuf, params);
    k_fused<<<GRID_F, 512, 0, stream>>>(mem, kbuf, params, w_prev, w_out,
                                        sPart, tPart, cnt1, edgeE, rpart);
    k_norm<<<B, 256, 0, stream>>>(tPart, rpart, w_out, r_out);
}

// Round 9
// 299.444 us; speedup vs baseline: 1.3882x; 1.3882x over previous
//
#include <hip/hip_runtime.h>
#include <math.h>

#define B 1024
#define N 2048
#define M 128
#define C 512
#define OD (M + 6)
#define EPSF 1e-8f
#define CHUNK 512
#define NCHUNK 4           // N / CHUNK
#define NGRP 64            // concurrent b-groups
#define ITERS (B / NGRP)   // 16
#define GRID_F (NCHUNK * NGRP)   // 256 blocks = 1/CU
#define AGENT __HIP_MEMORY_SCOPE_AGENT

__device__ __forceinline__ float softplusf(float x) {
    return fmaxf(x, 0.f) + log1pf(expf(-fabsf(x)));
}
__device__ __forceinline__ float sigmoidf_(float x) {
    return 1.f / (1.f + expf(-x));
}

// LDS-only barrier (no vmcnt drain)
__device__ __forceinline__ void bar_lds() {
    asm volatile("s_waitcnt lgkmcnt(0)" ::: "memory");
    __builtin_amdgcn_s_barrier();
}

// Kernel 1: o = x @ W.T + b; k (first M cols) + scalar head params.
__global__ __launch_bounds__(256) void k_head(
    const float* __restrict__ x, const float* __restrict__ W,
    const float* __restrict__ bias, float* __restrict__ kbuf,
    float* __restrict__ params)
{
    const int b = blockIdx.x;
    __shared__ float xs[C];
    __shared__ float os[OD];
    __shared__ float red[128];

    for (int i = threadIdx.x; i < C; i += 256) xs[i] = x[(size_t)b * C + i];
    __syncthreads();

    if (threadIdx.x < OD) {
        const int j = threadIdx.x;
        const float4* wr = (const float4*)(W + (size_t)j * C);
        float acc = 0.f;
#pragma unroll 8
        for (int c = 0; c < C / 4; ++c) {
            float4 wv = wr[c];
            acc = fmaf(wv.x, xs[4 * c + 0], acc);
            acc = fmaf(wv.y, xs[4 * c + 1], acc);
            acc = fmaf(wv.z, xs[4 * c + 2], acc);
            acc = fmaf(wv.w, xs[4 * c + 3], acc);
        }
        os[j] = acc + bias[j];
    }
    __syncthreads();

    if (threadIdx.x < M) {
        float v = os[threadIdx.x];
        kbuf[(size_t)b * M + threadIdx.x] = v;
        red[threadIdx.x] = v * v;
    }
    __syncthreads();
    for (int s = 64; s > 0; s >>= 1) {
        if (threadIdx.x < s) red[threadIdx.x] += red[threadIdx.x + s];
        __syncthreads();
    }
    if (threadIdx.x == 0) {
        float kn = sqrtf(red[0]);
        float beta = softplusf(os[M]);
        float g = sigmoidf_(os[M + 1]);
        float a0 = os[M + 2], a1 = os[M + 3], a2 = os[M + 4];
        float mx = fmaxf(a0, fmaxf(a1, a2));
        float e0 = expf(a0 - mx), e1 = expf(a1 - mx), e2 = expf(a2 - mx);
        float inv = 1.f / (e0 + e1 + e2);
        float gamma = 1.f + softplusf(os[M + 5]);
        float* p = params + (size_t)b * 8;
        p[0] = beta; p[1] = g; p[2] = e0 * inv; p[3] = e1 * inv;
        p[4] = e2 * inv; p[5] = gamma; p[6] = kn; p[7] = 0.f;
    }
}

// Single-mem-pass fused kernel v5 = R7 skeleton + LDS-transpose phase-A
// reduction (cuts per-thread DS ops ~160 -> ~33). 256 blocks (1/CU),
// 1024 threads (16 waves). Block (cid=blockIdx>>6, bgrp=blockIdx&63) owns
// chunk cid (512 rows) of b = bgrp*16+it. mem read exactly once; one
// relaxed-atomic sync per b. exp without max-subtract: |z| <= beta ~ small.
__global__ __launch_bounds__(1024, 4) void k_fused(
    const float* __restrict__ mem, const float* __restrict__ kbuf,
    const float* __restrict__ params, const float* __restrict__ w_prev,
    float* __restrict__ w_out,
    float* __restrict__ sPart, float* __restrict__ tPart,
    int* __restrict__ cnt1, float* __restrict__ edgeE,
    float* __restrict__ rpart)
{
    __shared__ float2 redT[CHUNK * 33];   // (dot,sq) partials, pad 33 vs 32
    __shared__ float eA[CHUNK];
    __shared__ float wgA[CHUNK + 2];
    __shared__ float pwA[CHUNK];
    __shared__ float redA[16 * 128];
    __shared__ float partS[16];
    __shared__ float partT[8];
    __shared__ float bcast[4];

    const int tid  = threadIdx.x;
    const int lane = tid & 63;
    const int wv   = tid >> 6;       // 0..15
    const int half = lane >> 5;
    const int l32  = lane & 31;
    const int hw   = wv * 2 + half;  // 0..31: half-wave id (16 rows each)

    const int cid  = blockIdx.x >> 6;       // 0..3
    const int bgrp = blockIdx.x & 63;       // peers share bgrp -> same XCD

    for (int it = 0; it < ITERS; ++it) {
        const int b = bgrp * ITERS + it;
        const float* cb = mem + ((size_t)b * N + cid * CHUNK) * M;

        // ---- issue chunk loads (64 MB aggregate burst across the chip) ----
        float4 frag[16];
#pragma unroll
        for (int j = 0; j < 16; ++j)
            frag[j] = ((const float4*)(cb + (size_t)(hw * 16 + j) * M))[l32];

        // small loads issued early; consumed in phase B
        float wp_t = 0.f, wpL = 0.f, wpR = 0.f;
        if (tid < CHUNK)
            wp_t = w_prev[(size_t)b * N + cid * CHUNK + tid];
        if (tid == 0) {
            wpL = w_prev[(size_t)b * N + ((cid * CHUNK + N - 1) & (N - 1))];
            wpR = w_prev[(size_t)b * N + ((cid * CHUNK + CHUNK) & (N - 1))];
        }
        const float4 kv = ((const float4*)(kbuf + (size_t)b * M))[l32];
        const float4 p0 = ((const float4*)(params + (size_t)b * 8))[0];
        const float4 p1 = ((const float4*)(params + (size_t)b * 8))[1];
        const float beta = p0.x, kn = p1.z;

        // ---- phase A1: per-row m-slice partials -> LDS (no shuffles) ----
#pragma unroll
        for (int j = 0; j < 16; ++j) {
            const float4 f = frag[j];
            const float dot = f.x * kv.x + f.y * kv.y + f.z * kv.z + f.w * kv.w;
            const float sq  = f.x * f.x + f.y * f.y + f.z * f.z + f.w * f.w;
            redT[(hw * 16 + j) * 33 + l32] = make_float2(dot, sq);
        }
        bar_lds();   // redT visible

        // ---- phase A2: transpose reduce, 2 threads per row ----
        {
            const int r = tid >> 1, q = tid & 1;
            const float2* rowp = &redT[r * 33 + q * 16];
            float dot = 0.f, sq = 0.f;
#pragma unroll
            for (int g = 0; g < 16; ++g) { dot += rowp[g].x; sq += rowp[g].y; }
            dot += __shfl_xor(dot, 1, 64);
            sq  += __shfl_xor(sq,  1, 64);
            float e = 0.f;
            if (q == 0) {
                const float z = beta * dot / (sqrtf(sq) * kn + EPSF);
                e = expf(z);
                eA[r] = e;
            }
            float myS = e;   // q==1 lanes contribute 0
#pragma unroll
            for (int s = 1; s <= 32; s <<= 1) myS += __shfl_xor(myS, s, 64);
            if (lane == 0) partS[wv] = myS;
        }
        bar_lds();   // bar1: eA/partS visible

        // ---- publish S_c + edge e's, arrive, spin (all relaxed) ----
        if (tid == 0) {
            float S = 0.f;
#pragma unroll
            for (int h = 0; h < 16; ++h) S += partS[h];
            __hip_atomic_store(&sPart[(size_t)b * NCHUNK + cid], S, __ATOMIC_RELAXED, AGENT);
            __hip_atomic_store(&edgeE[((size_t)b * NCHUNK + cid) * 2 + 0], eA[0], __ATOMIC_RELAXED, AGENT);
            __hip_atomic_store(&edgeE[((size_t)b * NCHUNK + cid) * 2 + 1], eA[CHUNK - 1], __ATOMIC_RELAXED, AGENT);
            asm volatile("s_waitcnt vmcnt(0)" ::: "memory");
            __hip_atomic_fetch_add(&cnt1[b], 1, __ATOMIC_RELAXED, AGENT);
            int tries = 0;
            while (__hip_atomic_load(&cnt1[b], __ATOMIC_RELAXED, AGENT) < NCHUNK) {
                __builtin_amdgcn_s_sleep(1);
                if (++tries > (1 << 22)) break;   // failsafe: fail loud, not hang
            }
            float St = 0.f;
#pragma unroll
            for (int c2 = 0; c2 < NCHUNK; ++c2)   // fixed order -> deterministic
                St += __hip_atomic_load(&sPart[(size_t)b * NCHUNK + c2], __ATOMIC_RELAXED, AGENT);
            bcast[0] = 1.f / St;
            bcast[1] = __hip_atomic_load(&edgeE[((size_t)b * NCHUNK + ((cid + NCHUNK - 1) & (NCHUNK - 1))) * 2 + 1], __ATOMIC_RELAXED, AGENT);
            bcast[2] = __hip_atomic_load(&edgeE[((size_t)b * NCHUNK + ((cid + 1) & (NCHUNK - 1))) * 2 + 0], __ATOMIC_RELAXED, AGENT);
        }
        bar_lds();   // bar2: bcast visible

        // ---- phase B: wg, conv3, pow, partial T ----
        const float invS = bcast[0], eL = bcast[1], eR = bcast[2];
        const float g = p0.y, s0p = p0.z, s1p = p0.w, s2p = p1.x, gamma = p1.y;
        if (tid < CHUNK)
            wgA[tid + 1] = g * eA[tid] * invS + (1.f - g) * wp_t;
        if (tid == 0) {
            wgA[0]         = g * eL * invS + (1.f - g) * wpL;
            wgA[CHUNK + 1] = g * eR * invS + (1.f - g) * wpR;
        }
        bar_lds();   // bar3: wgA visible

        float myT = 0.f;
        if (tid < CHUNK) {
            const float wt = s0p * wgA[tid] + s1p * wgA[tid + 1] + s2p * wgA[tid + 2];
            const float pw = powf(wt, gamma);
            pwA[tid] = pw;
            myT = pw;
        }
#pragma unroll
        for (int s = 32; s >= 1; s >>= 1) myT += __shfl_xor(myT, s, 64);
        if (lane == 0 && wv < 8) partT[wv] = myT;
        bar_lds();   // bar4: pwA/partT visible

        if (tid == 0) {
            float T = 0.f;
#pragma unroll
            for (int w2 = 0; w2 < 8; ++w2) T += partT[w2];
            tPart[(size_t)b * NCHUNK + cid] = T;   // plain store; kernel boundary syncs
        }

        // ---- phase C: unnormalized r partial from register-held chunk ----
        float4 pwv[4];
#pragma unroll
        for (int q4 = 0; q4 < 4; ++q4)
            pwv[q4] = ((const float4*)&pwA[hw * 16])[q4];   // broadcast reads
        float4 acc = make_float4(0.f, 0.f, 0.f, 0.f);
#pragma unroll
        for (int j = 0; j < 16; ++j) {
            const float pw = ((const float*)&pwv[j >> 2])[j & 3];
            acc.x = fmaf(pw, frag[j].x, acc.x);
            acc.y = fmaf(pw, frag[j].y, acc.y);
            acc.z = fmaf(pw, frag[j].z, acc.z);
            acc.w = fmaf(pw, frag[j].w, acc.w);
        }
        acc.x += __shfl_xor(acc.x, 32, 64);
        acc.y += __shfl_xor(acc.y, 32, 64);
        acc.z += __shfl_xor(acc.z, 32, 64);
        acc.w += __shfl_xor(acc.w, 32, 64);
        if (half == 0) *(float4*)&redA[wv * 128 + l32 * 4] = acc;
        bar_lds();   // bar5: redA visible

        if (tid < 128) {
            float s = 0.f;
#pragma unroll
            for (int w2 = 0; w2 < 16; ++w2) s += redA[w2 * 128 + tid];
            rpart[((size_t)b * NCHUNK + cid) * 128 + tid] = s;   // plain store
        }
        // ---- phase D: unnormalized w slice (k_norm scales in place) ----
        if (tid < CHUNK)
            w_out[(size_t)b * N + cid * CHUNK + tid] = pwA[tid];
        bar_lds();   // protect LDS reuse across iterations
    }
}

// Tiny epilogue: per b, T = sum of chunk partials; scale w in place; reduce r.
__global__ __launch_bounds__(256) void k_norm(
    const float* __restrict__ tPart, const float* __restrict__ rpart,
    float* __restrict__ w_out, float* __restrict__ r_out)
{
    const int b = blockIdx.x, tid = threadIdx.x;
    float T = 0.f;
#pragma unroll
    for (int c = 0; c < NCHUNK; ++c) T += tPart[(size_t)b * NCHUNK + c];
    const float invT = 1.f / (T + 1e-16f);

    float4* w4 = (float4*)(w_out + (size_t)b * N);
#pragma unroll
    for (int k = 0; k < 2; ++k) {
        float4 v = w4[tid + k * 256];
        v.x *= invT; v.y *= invT; v.z *= invT; v.w *= invT;
        w4[tid + k * 256] = v;
    }
    if (tid < 128) {
        float s = 0.f;
#pragma unroll
        for (int c = 0; c < NCHUNK; ++c)   // fixed order -> deterministic
            s += rpart[((size_t)b * NCHUNK + c) * 128 + tid];
        r_out[(size_t)b * M + tid] = s * invT;
    }
}

extern "C" void kernel_launch(void* const* d_in, const int* in_sizes, int n_in,
                              void* d_out, int out_size, void* d_ws, size_t ws_size,
                              hipStream_t stream) {
    const float* x      = (const float*)d_in[0];
    const float* w_prev = (const float*)d_in[1];
    const float* mem    = (const float*)d_in[2];
    const float* W      = (const float*)d_in[3];
    const float* bias   = (const float*)d_in[4];

    float* r_out = (float*)d_out;                 // B*M
    float* w_out = (float*)d_out + (size_t)B * M; // B*N

    float* ws     = (float*)d_ws;
    float* kbuf   = ws;                                    // B*M
    float* params = kbuf + (size_t)B * M;                  // B*8
    float* sPart  = params + (size_t)B * 8;                // B*NCHUNK
    float* tPart  = sPart + (size_t)B * NCHUNK;            // B*NCHUNK
    int*   cnt1   = (int*)(tPart + (size_t)B * NCHUNK);    // B ints
    float* edgeE  = (float*)(cnt1 + B);                    // B*NCHUNK*2
    float* rpart  = edgeE + (size_t)B * NCHUNK * 2;        // B*NCHUNK*128

    // arrival counters must be zero every call
    hipMemsetAsync(cnt1, 0, B * sizeof(int), stream);

    k_head<<<B, 256, 0, stream>>>(x, W, bias, kbuf, params);
    k_fused<<<GRID_F, 1024, 0, stream>>>(mem, kbuf, params, w_prev, w_out,
                                         sPart, tPart, cnt1, edgeE, rpart);
    k_norm<<<B, 256, 0, stream>>>(tPart, rpart, w_out, r_out);
}